// Round 1
// baseline (135.310 us; speedup 1.0000x reference)
//
#include <hip/hip_runtime.h>

#define NBINS 15

// Workspace layout (u64 each): [0..14] sum(conf_q), [15..29] count,
// [30..44] sum(correct), [45] total mask sum. 368 bytes.

__global__ __launch_bounds__(256) void ece_partial(
    const float* __restrict__ conf,
    const int*   __restrict__ pred,
    const int*   __restrict__ targ,
    const int*   __restrict__ mask,
    unsigned long long* __restrict__ ws,
    long long nvec, long long n)
{
    // Per-wave packed histograms: [wave][bin], padded to 16.
    __shared__ unsigned long long h[4][16];
    __shared__ unsigned long long stot;

    const int tid = threadIdx.x;
    const int wid = tid >> 6;

    if (tid < 64) h[tid >> 4][tid & 15] = 0ULL;
    if (tid == 0) stot = 0ULL;
    __syncthreads();

    const long long gid    = (long long)blockIdx.x * blockDim.x + tid;
    const long long stride = (long long)gridDim.x * blockDim.x;

    const float4* __restrict__ c4p = (const float4*)conf;
    const int4*   __restrict__ p4p = (const int4*)pred;
    const int4*   __restrict__ t4p = (const int4*)targ;
    const int4*   __restrict__ m4p = (const int4*)mask;

    unsigned int tot = 0;

    for (long long i = gid; i < nvec; i += stride) {
        float4 c4 = c4p[i];
        int4   p4 = p4p[i];
        int4   t4 = t4p[i];
        int4   m4 = m4p[i];
#pragma unroll
        for (int k = 0; k < 4; ++k) {
            float c = (&c4.x)[k];
            int   m = (&m4.x)[k];
            int   p = (&p4.x)[k];
            int   t = (&t4.x)[k];
            tot += (unsigned int)m;
            bool valid = (m != 0) && (c > 0.0f) && (c <= 1.0f);
            if (valid) {
                int bin = (int)ceilf(c * 15.0f) - 1;
                bin = min(max(bin, 0), NBINS - 1);
                unsigned long long corr = (p == t) ? 1ULL : 0ULL;
                unsigned int cq = (unsigned int)(c * 65536.0f + 0.5f); // <= 65536
                // fields: [0:32) sum(conf_q)  [32:47) count  [47:62) correct
                unsigned long long pk =
                    (unsigned long long)cq | (1ULL << 32) | (corr << 47);
                atomicAdd(&h[wid][bin], pk);
            }
        }
    }

    // Scalar tail if n % 4 != 0 (not the case here, but be safe).
    if (gid == 0) {
        for (long long i = nvec * 4; i < n; ++i) {
            float c = conf[i];
            int   m = mask[i];
            tot += (unsigned int)m;
            bool valid = (m != 0) && (c > 0.0f) && (c <= 1.0f);
            if (valid) {
                int bin = (int)ceilf(c * 15.0f) - 1;
                bin = min(max(bin, 0), NBINS - 1);
                unsigned long long corr = (pred[i] == targ[i]) ? 1ULL : 0ULL;
                unsigned int cq = (unsigned int)(c * 65536.0f + 0.5f);
                unsigned long long pk =
                    (unsigned long long)cq | (1ULL << 32) | (corr << 47);
                atomicAdd(&h[0][bin], pk);
            }
        }
    }

    // Reduce total-mask across the wave, then block, then device.
    unsigned int v = tot;
#pragma unroll
    for (int off = 32; off; off >>= 1) v += __shfl_down(v, off, 64);
    if ((tid & 63) == 0) atomicAdd(&stot, (unsigned long long)v);

    __syncthreads();

    if (tid < NBINS) {
        unsigned long long s = h[0][tid] + h[1][tid] + h[2][tid] + h[3][tid];
        if (s) {
            unsigned long long confq = s & 0xFFFFFFFFULL;        // <= 2^30 per block
            unsigned long long cnt   = (s >> 32) & 0x7FFFULL;    // <= 16384 per block
            unsigned long long corr  = s >> 47;                  // <= 16384 per block
            atomicAdd(&ws[tid], confq);
            atomicAdd(&ws[NBINS + tid], cnt);
            atomicAdd(&ws[2 * NBINS + tid], corr);
        }
    }
    if (tid == 0) {
        unsigned long long s = stot;
        if (s) atomicAdd(&ws[3 * NBINS], s);
    }
}

__global__ void ece_final(const unsigned long long* __restrict__ ws,
                          float* __restrict__ out)
{
    int tid = threadIdx.x; // 64 threads
    double v = 0.0;
    if (tid < NBINS) {
        unsigned long long cnt = ws[NBINS + tid];
        if (cnt > 0) {
            double confs = (double)ws[tid] * (1.0 / 65536.0);
            double corr  = (double)ws[2 * NBINS + tid];
            // |avg_conf - acc| * cnt = |sum_conf - sum_corr| (safe==cnt here)
            v = fabs(confs - corr);
        }
    }
#pragma unroll
    for (int off = 32; off; off >>= 1) v += __shfl_down(v, off, 64);
    if (tid == 0) {
        double total = (double)ws[3 * NBINS];
        if (total < 1.0) total = 1.0;
        out[0] = (float)(v / total);
    }
}

extern "C" void kernel_launch(void* const* d_in, const int* in_sizes, int n_in,
                              void* d_out, int out_size, void* d_ws, size_t ws_size,
                              hipStream_t stream)
{
    const float* conf = (const float*)d_in[0];
    const int*   pred = (const int*)d_in[1];
    const int*   targ = (const int*)d_in[2];
    const int*   mask = (const int*)d_in[3];
    long long n    = in_sizes[0];
    long long nvec = n / 4;

    unsigned long long* ws = (unsigned long long*)d_ws;

    // Zero the 46 u64 accumulators every call (deterministic; capture-safe).
    hipMemsetAsync(d_ws, 0, (3 * NBINS + 1) * sizeof(unsigned long long), stream);

    // 2048 blocks x 256 threads: 16 float4-iters/thread at n=33.55M;
    // per-wave element count 4096 keeps all packed fields far from overflow.
    ece_partial<<<2048, 256, 0, stream>>>(conf, pred, targ, mask, ws, nvec, n);
    ece_final<<<1, 64, 0, stream>>>(ws, (float*)d_out);
}

// Round 2
// 128.013 us; speedup vs baseline: 1.0570x; 1.0570x over previous
//
#include <hip/hip_runtime.h>

#define NBINS 15

// Workspace layout (u64 each): [0..14] sum(conf_q), [15..29] count,
// [30..44] sum(correct), [45] total mask sum. 368 bytes.

__global__ __launch_bounds__(256, 8) void ece_partial(
    const float* __restrict__ conf,
    const int*   __restrict__ pred,
    const int*   __restrict__ targ,
    const int*   __restrict__ mask,
    unsigned long long* __restrict__ ws,
    int nvec)
{
    // Per-wave packed histograms: [wave][bin], padded to 16.
    __shared__ unsigned long long h[4][16];
    __shared__ unsigned long long stot;

    const int tid = threadIdx.x;
    const int wid = tid >> 6;

    if (tid < 64) h[tid >> 4][tid & 15] = 0ULL;
    if (tid == 0) stot = 0ULL;
    __syncthreads();

    const int gid    = blockIdx.x * blockDim.x + tid;
    const int stride = gridDim.x * blockDim.x;

    const float4* __restrict__ c4p = (const float4*)conf;
    const int4*   __restrict__ p4p = (const int4*)pred;
    const int4*   __restrict__ t4p = (const int4*)targ;
    const int4*   __restrict__ m4p = (const int4*)mask;

    unsigned int tot = 0;

    // Main loop: two independent float4/int4 chunks per array in flight
    // (8 outstanding vector loads per wave -> MLP to cover HBM latency).
    int i = gid;
    for (; i + stride < nvec; i += 2 * stride) {
        const int j = i + stride;
        // Issue all 8 loads before any consumption.
        float4 c0 = c4p[i];
        float4 c1 = c4p[j];
        int4   p0 = p4p[i];
        int4   p1 = p4p[j];
        int4   t0 = t4p[i];
        int4   t1 = t4p[j];
        int4   m0 = m4p[i];
        int4   m1 = m4p[j];

#pragma unroll
        for (int k = 0; k < 4; ++k) {
            float c = (&c0.x)[k];
            int   m = (&m0.x)[k];
            tot += (unsigned int)m;
            bool valid = (m != 0) && (c > 0.0f) && (c <= 1.0f);
            if (valid) {
                int bin = (int)ceilf(c * 15.0f) - 1;
                bin = min(max(bin, 0), NBINS - 1);
                unsigned long long corr = ((&p0.x)[k] == (&t0.x)[k]) ? 1ULL : 0ULL;
                unsigned int cq = (unsigned int)(c * 65536.0f + 0.5f); // <= 65536
                // fields: [0:32) sum(conf_q)  [32:47) count  [47:62) correct
                unsigned long long pk =
                    (unsigned long long)cq | (1ULL << 32) | (corr << 47);
                atomicAdd(&h[wid][bin], pk);
            }
        }
#pragma unroll
        for (int k = 0; k < 4; ++k) {
            float c = (&c1.x)[k];
            int   m = (&m1.x)[k];
            tot += (unsigned int)m;
            bool valid = (m != 0) && (c > 0.0f) && (c <= 1.0f);
            if (valid) {
                int bin = (int)ceilf(c * 15.0f) - 1;
                bin = min(max(bin, 0), NBINS - 1);
                unsigned long long corr = ((&p1.x)[k] == (&t1.x)[k]) ? 1ULL : 0ULL;
                unsigned int cq = (unsigned int)(c * 65536.0f + 0.5f);
                unsigned long long pk =
                    (unsigned long long)cq | (1ULL << 32) | (corr << 47);
                atomicAdd(&h[wid][bin], pk);
            }
        }
    }
    // Remainder: single-chunk iterations.
    for (; i < nvec; i += stride) {
        float4 c0 = c4p[i];
        int4   p0 = p4p[i];
        int4   t0 = t4p[i];
        int4   m0 = m4p[i];
#pragma unroll
        for (int k = 0; k < 4; ++k) {
            float c = (&c0.x)[k];
            int   m = (&m0.x)[k];
            tot += (unsigned int)m;
            bool valid = (m != 0) && (c > 0.0f) && (c <= 1.0f);
            if (valid) {
                int bin = (int)ceilf(c * 15.0f) - 1;
                bin = min(max(bin, 0), NBINS - 1);
                unsigned long long corr = ((&p0.x)[k] == (&t0.x)[k]) ? 1ULL : 0ULL;
                unsigned int cq = (unsigned int)(c * 65536.0f + 0.5f);
                unsigned long long pk =
                    (unsigned long long)cq | (1ULL << 32) | (corr << 47);
                atomicAdd(&h[wid][bin], pk);
            }
        }
    }

    // Reduce total-mask across the wave, then block, then device.
    unsigned int v = tot;
#pragma unroll
    for (int off = 32; off; off >>= 1) v += __shfl_down(v, off, 64);
    if ((tid & 63) == 0) atomicAdd(&stot, (unsigned long long)v);

    __syncthreads();

    if (tid < NBINS) {
        unsigned long long s = h[0][tid] + h[1][tid] + h[2][tid] + h[3][tid];
        if (s) {
            unsigned long long confq = s & 0xFFFFFFFFULL;        // <= 2^30 per block
            unsigned long long cnt   = (s >> 32) & 0x7FFFULL;    // <= 16384 per block
            unsigned long long corr  = s >> 47;                  // <= 16384 per block
            atomicAdd(&ws[tid], confq);
            atomicAdd(&ws[NBINS + tid], cnt);
            atomicAdd(&ws[2 * NBINS + tid], corr);
        }
    }
    if (tid == 0) {
        unsigned long long s = stot;
        if (s) atomicAdd(&ws[3 * NBINS], s);
    }
}

__global__ void ece_scalar_tail(const float* __restrict__ conf,
                                const int*   __restrict__ pred,
                                const int*   __restrict__ targ,
                                const int*   __restrict__ mask,
                                unsigned long long* __restrict__ ws,
                                long long start, long long n)
{
    // Handles n % 4 != 0 leftovers (none for this problem's shape).
    long long i = start + threadIdx.x;
    if (i < n) {
        float c = conf[i];
        int   m = mask[i];
        if (m) atomicAdd(&ws[3 * NBINS], 1ULL);
        bool valid = (m != 0) && (c > 0.0f) && (c <= 1.0f);
        if (valid) {
            int bin = (int)ceilf(c * 15.0f) - 1;
            bin = min(max(bin, 0), NBINS - 1);
            unsigned long long corr = (pred[i] == targ[i]) ? 1ULL : 0ULL;
            unsigned int cq = (unsigned int)(c * 65536.0f + 0.5f);
            atomicAdd(&ws[bin], (unsigned long long)cq);
            atomicAdd(&ws[NBINS + bin], 1ULL);
            atomicAdd(&ws[2 * NBINS + bin], corr);
        }
    }
}

__global__ void ece_final(const unsigned long long* __restrict__ ws,
                          float* __restrict__ out)
{
    int tid = threadIdx.x; // 64 threads
    double v = 0.0;
    if (tid < NBINS) {
        unsigned long long cnt = ws[NBINS + tid];
        if (cnt > 0) {
            double confs = (double)ws[tid] * (1.0 / 65536.0);
            double corr  = (double)ws[2 * NBINS + tid];
            // |avg_conf - acc| * cnt = |sum_conf - sum_corr| (safe==cnt here)
            v = fabs(confs - corr);
        }
    }
#pragma unroll
    for (int off = 32; off; off >>= 1) v += __shfl_down(v, off, 64);
    if (tid == 0) {
        double total = (double)ws[3 * NBINS];
        if (total < 1.0) total = 1.0;
        out[0] = (float)(v / total);
    }
}

extern "C" void kernel_launch(void* const* d_in, const int* in_sizes, int n_in,
                              void* d_out, int out_size, void* d_ws, size_t ws_size,
                              hipStream_t stream)
{
    const float* conf = (const float*)d_in[0];
    const int*   pred = (const int*)d_in[1];
    const int*   targ = (const int*)d_in[2];
    const int*   mask = (const int*)d_in[3];
    long long n    = in_sizes[0];
    int       nvec = (int)(n / 4);

    unsigned long long* ws = (unsigned long long*)d_ws;

    // Zero the 46 u64 accumulators every call (deterministic; capture-safe).
    hipMemsetAsync(d_ws, 0, (3 * NBINS + 1) * sizeof(unsigned long long), stream);

    // 2048 blocks x 256 threads = 8 blocks/CU; 16 float4-chunks per thread,
    // consumed 2-at-a-time for 8 outstanding loads per wave.
    ece_partial<<<2048, 256, 0, stream>>>(conf, pred, targ, mask, ws, nvec);
    if (n % 4 != 0) {
        ece_scalar_tail<<<1, 64, 0, stream>>>(conf, pred, targ, mask, ws,
                                              (long long)nvec * 4, n);
    }
    ece_final<<<1, 64, 0, stream>>>(ws, (float*)d_out);
}

// Round 3
// 118.230 us; speedup vs baseline: 1.1445x; 1.0827x over previous
//
#include <hip/hip_runtime.h>

#define NBINS 15

typedef float f32x4 __attribute__((ext_vector_type(4)));
typedef int   i32x4 __attribute__((ext_vector_type(4)));

// Workspace layout (u64 each): [0..14] per-bin signed sum of wv*(c-corr) in
// 2^-16 fixed point (two's-complement wrapped), [15] total mask sum.
// ECE = sum_b |S_b| / 2^16 / total.  (counts/safe are provably redundant:
// empty bins contribute 0 to both formulations.)

__global__ __launch_bounds__(256, 8) void ece_partial(
    const float* __restrict__ conf,
    const int*   __restrict__ pred,
    const int*   __restrict__ targ,
    const int*   __restrict__ mask,
    unsigned long long* __restrict__ ws,
    int nvec)
{
    // Per-wave signed fixed-point bin sums (u32 wraparound == signed add).
    __shared__ unsigned int h[4][16];
    __shared__ unsigned long long stot;

    const int tid = threadIdx.x;
    const int wid = tid >> 6;

    if (tid < 64) h[tid >> 4][tid & 15] = 0u;
    if (tid == 0) stot = 0ULL;
    __syncthreads();

    const int gid    = blockIdx.x * blockDim.x + tid;
    const int stride = gridDim.x * blockDim.x;

    const f32x4* __restrict__ c4p = (const f32x4*)conf;
    const i32x4* __restrict__ p4p = (const i32x4*)pred;
    const i32x4* __restrict__ t4p = (const i32x4*)targ;
    const i32x4* __restrict__ m4p = (const i32x4*)mask;

    unsigned int tot = 0;

    int i = gid;
    for (; i + stride < nvec; i += 2 * stride) {
        const int j = i + stride;
        f32x4 c0 = c4p[i];
        f32x4 c1 = c4p[j];
        i32x4 p0 = p4p[i];
        i32x4 p1 = p4p[j];
        i32x4 t0 = t4p[i];
        i32x4 t1 = t4p[j];
        i32x4 m0 = m4p[i];
        i32x4 m1 = m4p[j];
        // Pin all 8 vector loads live here: forbids the compiler from
        // re-serializing them to save VGPRs (it did exactly that in R2,
        // leaving ~1 load in flight -> latency-bound at 20% HBM).
        asm volatile("" : "+v"(c0), "+v"(c1), "+v"(p0), "+v"(p1),
                          "+v"(t0), "+v"(t1), "+v"(m0), "+v"(m1));

#pragma unroll
        for (int k = 0; k < 4; ++k) {
            float c = c0[k];
            int   m = m0[k];
            tot += (unsigned int)m;
            if ((m != 0) & (c > 0.0f) & (c <= 1.0f)) {
                int bin = (int)ceilf(c * 15.0f) - 1;
                bin = min(max(bin, 0), NBINS - 1);
                float corr = (p0[k] == t0[k]) ? 1.0f : 0.0f;
                int d = (int)rintf((c - corr) * 65536.0f); // |d| <= 65536
                atomicAdd(&h[wid][bin], (unsigned int)d);
            }
        }
#pragma unroll
        for (int k = 0; k < 4; ++k) {
            float c = c1[k];
            int   m = m1[k];
            tot += (unsigned int)m;
            if ((m != 0) & (c > 0.0f) & (c <= 1.0f)) {
                int bin = (int)ceilf(c * 15.0f) - 1;
                bin = min(max(bin, 0), NBINS - 1);
                float corr = (p1[k] == t1[k]) ? 1.0f : 0.0f;
                int d = (int)rintf((c - corr) * 65536.0f);
                atomicAdd(&h[wid][bin], (unsigned int)d);
            }
        }
    }
    for (; i < nvec; i += stride) {
        f32x4 c0 = c4p[i];
        i32x4 p0 = p4p[i];
        i32x4 t0 = t4p[i];
        i32x4 m0 = m4p[i];
#pragma unroll
        for (int k = 0; k < 4; ++k) {
            float c = c0[k];
            int   m = m0[k];
            tot += (unsigned int)m;
            if ((m != 0) & (c > 0.0f) & (c <= 1.0f)) {
                int bin = (int)ceilf(c * 15.0f) - 1;
                bin = min(max(bin, 0), NBINS - 1);
                float corr = (p0[k] == t0[k]) ? 1.0f : 0.0f;
                int d = (int)rintf((c - corr) * 65536.0f);
                atomicAdd(&h[wid][bin], (unsigned int)d);
            }
        }
    }

    // Total-mask: wave shuffle reduce -> LDS -> one global atomic per block.
    unsigned int v = tot;
#pragma unroll
    for (int off = 32; off; off >>= 1) v += __shfl_down(v, off, 64);
    if ((tid & 63) == 0) atomicAdd(&stot, (unsigned long long)v);

    __syncthreads();

    if (tid < NBINS) {
        // Sum 4 per-wave wrapped-i32 partials (block |sum| <= 2^30, fits i32),
        // sign-extend, accumulate into global i64 (u64 wraparound-safe).
        int s = (int)(h[0][tid] + h[1][tid] + h[2][tid] + h[3][tid]);
        if (s != 0)
            atomicAdd(&ws[tid], (unsigned long long)(long long)s);
    }
    if (tid == 0) {
        unsigned long long s = stot;
        if (s) atomicAdd(&ws[NBINS], s);
    }
}

__global__ void ece_scalar_tail(const float* __restrict__ conf,
                                const int*   __restrict__ pred,
                                const int*   __restrict__ targ,
                                const int*   __restrict__ mask,
                                unsigned long long* __restrict__ ws,
                                long long start, long long n)
{
    long long i = start + threadIdx.x;
    if (i < n) {
        float c = conf[i];
        int   m = mask[i];
        if (m) atomicAdd(&ws[NBINS], 1ULL);
        if ((m != 0) & (c > 0.0f) & (c <= 1.0f)) {
            int bin = (int)ceilf(c * 15.0f) - 1;
            bin = min(max(bin, 0), NBINS - 1);
            float corr = (pred[i] == targ[i]) ? 1.0f : 0.0f;
            int d = (int)rintf((c - corr) * 65536.0f);
            atomicAdd(&ws[bin], (unsigned long long)(long long)d);
        }
    }
}

__global__ void ece_final(const unsigned long long* __restrict__ ws,
                          float* __restrict__ out)
{
    int tid = threadIdx.x; // 64 threads
    double v = 0.0;
    if (tid < NBINS) {
        long long s = (long long)ws[tid];
        v = fabs((double)s);
    }
#pragma unroll
    for (int off = 32; off; off >>= 1) v += __shfl_down(v, off, 64);
    if (tid == 0) {
        double total = (double)ws[NBINS];
        if (total < 1.0) total = 1.0;
        out[0] = (float)(v * (1.0 / 65536.0) / total);
    }
}

extern "C" void kernel_launch(void* const* d_in, const int* in_sizes, int n_in,
                              void* d_out, int out_size, void* d_ws, size_t ws_size,
                              hipStream_t stream)
{
    const float* conf = (const float*)d_in[0];
    const int*   pred = (const int*)d_in[1];
    const int*   targ = (const int*)d_in[2];
    const int*   mask = (const int*)d_in[3];
    long long n    = in_sizes[0];
    int       nvec = (int)(n / 4);

    unsigned long long* ws = (unsigned long long*)d_ws;

    // Zero the 16 u64 accumulators every call (deterministic; capture-safe).
    hipMemsetAsync(d_ws, 0, (NBINS + 1) * sizeof(unsigned long long), stream);

    // 2048 blocks x 256 threads = 8 blocks/CU resident; 16 float4-chunks per
    // thread, consumed 2-at-a-time with all 8 loads pinned in flight.
    ece_partial<<<2048, 256, 0, stream>>>(conf, pred, targ, mask, ws, nvec);
    if (n % 4 != 0) {
        ece_scalar_tail<<<1, 64, 0, stream>>>(conf, pred, targ, mask, ws,
                                              (long long)nvec * 4, n);
    }
    ece_final<<<1, 64, 0, stream>>>(ws, (float*)d_out);
}

// Round 4
// 116.585 us; speedup vs baseline: 1.1606x; 1.0141x over previous
//
#include <hip/hip_runtime.h>

#define NBINS 15

typedef float f32x4 __attribute__((ext_vector_type(4)));
typedef int   i32x4 __attribute__((ext_vector_type(4)));

// Workspace layout (u64 each): [0..14] per-bin signed sum of wv*(c-corr) in
// 2^-16 fixed point (two's-complement wrapped), [15] total mask sum.
// ECE = sum_b |S_b| / 2^16 / total.  (counts/safe are provably redundant:
// empty bins contribute 0 in both formulations.)

__global__ __launch_bounds__(256, 6) void ece_partial(
    const float* __restrict__ conf,
    const int*   __restrict__ pred,
    const int*   __restrict__ targ,
    const int*   __restrict__ mask,
    unsigned long long* __restrict__ ws,
    int nvec)
{
    // Block-level merge buffers only -- NO LDS ops in the hot loop.
    __shared__ unsigned int hsum[16];          // wrapped-i32 per-bin block sums
    __shared__ unsigned long long stot;

    const int tid  = threadIdx.x;
    const int lane = tid & 63;

    if (tid < 16) hsum[tid] = 0u;
    if (tid == 0) stot = 0ULL;
    __syncthreads();

    const int gid    = blockIdx.x * blockDim.x + tid;
    const int stride = gridDim.x * blockDim.x;

    const f32x4* __restrict__ c4p = (const f32x4*)conf;
    const i32x4* __restrict__ p4p = (const i32x4*)pred;
    const i32x4* __restrict__ t4p = (const i32x4*)targ;
    const i32x4* __restrict__ m4p = (const i32x4*)mask;

    // 15 private accumulators, ALL indexing compile-time after unroll.
    int acc[NBINS];
#pragma unroll
    for (int b = 0; b < NBINS; ++b) acc[b] = 0;

    unsigned int tot = 0;

    int i = gid;
    for (; i + stride < nvec; i += 2 * stride) {
        const int j = i + stride;
        f32x4 c0 = c4p[i];
        f32x4 c1 = c4p[j];
        i32x4 p0 = p4p[i];
        i32x4 p1 = p4p[j];
        i32x4 t0 = t4p[i];
        i32x4 t1 = t4p[j];
        i32x4 m0 = m4p[i];
        i32x4 m1 = m4p[j];
        // Keep all 8 vector loads issued before consumption (MLP).
        asm volatile("" : "+v"(c0), "+v"(c1), "+v"(p0), "+v"(p1),
                          "+v"(t0), "+v"(t1), "+v"(m0), "+v"(m1));

#pragma unroll
        for (int k = 0; k < 4; ++k) {
            float c = c0[k];
            int   m = m0[k];
            tot += (unsigned int)m;
            bool valid = (m != 0) & (c > 0.0f) & (c <= 1.0f);
            int bin = (int)ceilf(c * 15.0f) - 1;
            bin = min(max(bin, 0), NBINS - 1);
            bin = valid ? bin : -1;                       // -1 matches no bin
            float corr = (p0[k] == t0[k]) ? 1.0f : 0.0f;
            int d = (int)rintf((c - corr) * 65536.0f);    // |d| <= 65536
#pragma unroll
            for (int b = 0; b < NBINS; ++b)
                acc[b] += (bin == b) ? d : 0;             // branchless select
        }
#pragma unroll
        for (int k = 0; k < 4; ++k) {
            float c = c1[k];
            int   m = m1[k];
            tot += (unsigned int)m;
            bool valid = (m != 0) & (c > 0.0f) & (c <= 1.0f);
            int bin = (int)ceilf(c * 15.0f) - 1;
            bin = min(max(bin, 0), NBINS - 1);
            bin = valid ? bin : -1;
            float corr = (p1[k] == t1[k]) ? 1.0f : 0.0f;
            int d = (int)rintf((c - corr) * 65536.0f);
#pragma unroll
            for (int b = 0; b < NBINS; ++b)
                acc[b] += (bin == b) ? d : 0;
        }
    }
    for (; i < nvec; i += stride) {
        f32x4 c0 = c4p[i];
        i32x4 p0 = p4p[i];
        i32x4 t0 = t4p[i];
        i32x4 m0 = m4p[i];
#pragma unroll
        for (int k = 0; k < 4; ++k) {
            float c = c0[k];
            int   m = m0[k];
            tot += (unsigned int)m;
            bool valid = (m != 0) & (c > 0.0f) & (c <= 1.0f);
            int bin = (int)ceilf(c * 15.0f) - 1;
            bin = min(max(bin, 0), NBINS - 1);
            bin = valid ? bin : -1;
            float corr = (p0[k] == t0[k]) ? 1.0f : 0.0f;
            int d = (int)rintf((c - corr) * 65536.0f);
#pragma unroll
            for (int b = 0; b < NBINS; ++b)
                acc[b] += (bin == b) ? d : 0;
        }
    }

    // Once-per-block merge. Wave shuffle-reduce each accumulator, then the
    // wave leader does 15 LDS atomics (4 waves x 15 RMWs -- negligible).
#pragma unroll
    for (int b = 0; b < NBINS; ++b) {
        int v = acc[b];
#pragma unroll
        for (int off = 32; off; off >>= 1) v += __shfl_down(v, off, 64);
        acc[b] = v;
    }
    unsigned int v = tot;
#pragma unroll
    for (int off = 32; off; off >>= 1) v += __shfl_down(v, off, 64);

    if (lane == 0) {
#pragma unroll
        for (int b = 0; b < NBINS; ++b)
            if (acc[b] != 0) atomicAdd(&hsum[b], (unsigned int)acc[b]);
        atomicAdd(&stot, (unsigned long long)v);
    }
    __syncthreads();

    if (tid < NBINS) {
        int s = (int)hsum[tid];   // block |sum| <= 2^30, fits i32
        if (s != 0)
            atomicAdd(&ws[tid], (unsigned long long)(long long)s);
    }
    if (tid == 0) {
        unsigned long long s = stot;
        if (s) atomicAdd(&ws[NBINS], s);
    }
}

__global__ void ece_scalar_tail(const float* __restrict__ conf,
                                const int*   __restrict__ pred,
                                const int*   __restrict__ targ,
                                const int*   __restrict__ mask,
                                unsigned long long* __restrict__ ws,
                                long long start, long long n)
{
    long long i = start + threadIdx.x;
    if (i < n) {
        float c = conf[i];
        int   m = mask[i];
        if (m) atomicAdd(&ws[NBINS], 1ULL);
        if ((m != 0) & (c > 0.0f) & (c <= 1.0f)) {
            int bin = (int)ceilf(c * 15.0f) - 1;
            bin = min(max(bin, 0), NBINS - 1);
            float corr = (pred[i] == targ[i]) ? 1.0f : 0.0f;
            int d = (int)rintf((c - corr) * 65536.0f);
            atomicAdd(&ws[bin], (unsigned long long)(long long)d);
        }
    }
}

__global__ void ece_final(const unsigned long long* __restrict__ ws,
                          float* __restrict__ out)
{
    int tid = threadIdx.x; // 64 threads
    double v = 0.0;
    if (tid < NBINS) {
        long long s = (long long)ws[tid];
        v = fabs((double)s);
    }
#pragma unroll
    for (int off = 32; off; off >>= 1) v += __shfl_down(v, off, 64);
    if (tid == 0) {
        double total = (double)ws[NBINS];
        if (total < 1.0) total = 1.0;
        out[0] = (float)(v * (1.0 / 65536.0) / total);
    }
}

extern "C" void kernel_launch(void* const* d_in, const int* in_sizes, int n_in,
                              void* d_out, int out_size, void* d_ws, size_t ws_size,
                              hipStream_t stream)
{
    const float* conf = (const float*)d_in[0];
    const int*   pred = (const int*)d_in[1];
    const int*   targ = (const int*)d_in[2];
    const int*   mask = (const int*)d_in[3];
    long long n    = in_sizes[0];
    int       nvec = (int)(n / 4);

    unsigned long long* ws = (unsigned long long*)d_ws;

    // Zero the 16 u64 accumulators every call (deterministic; capture-safe).
    hipMemsetAsync(d_ws, 0, (NBINS + 1) * sizeof(unsigned long long), stream);

    // 1536 blocks x 256 threads = 6 blocks/CU resident (launch_bounds 256,6
    // caps at 85 VGPR: 32 payload + 15 acc + temps fits without spill).
    ece_partial<<<1536, 256, 0, stream>>>(conf, pred, targ, mask, ws, nvec);
    if (n % 4 != 0) {
        ece_scalar_tail<<<1, 64, 0, stream>>>(conf, pred, targ, mask, ws,
                                              (long long)nvec * 4, n);
    }
    ece_final<<<1, 64, 0, stream>>>(ws, (float*)d_out);
}

// Round 5
// 112.389 us; speedup vs baseline: 1.2039x; 1.0373x over previous
//
#include <hip/hip_runtime.h>

#define NBINS 15

typedef float f32x4 __attribute__((ext_vector_type(4)));
typedef int   i32x4 __attribute__((ext_vector_type(4)));

// Workspace layout (u64 each): [0..14] per-bin signed sum of wv*(c-corr) in
// 2^-16 fixed point (two's-complement wrapped), [15] total mask sum.
// ECE = sum_b |S_b| / 2^16 / total.  (counts/safe are provably redundant:
// empty bins contribute 0 in both formulations.)

__global__ __launch_bounds__(256, 6) void ece_partial(
    const float* __restrict__ conf,
    const int*   __restrict__ pred,
    const int*   __restrict__ targ,
    const int*   __restrict__ mask,
    unsigned long long* __restrict__ ws,
    int nvec)
{
    // Block-level merge buffers only -- NO LDS ops in the hot loop.
    __shared__ unsigned int hsum[16];          // wrapped-i32 per-bin block sums
    __shared__ unsigned long long stot;

    const int tid  = threadIdx.x;
    const int lane = tid & 63;

    if (tid < 16) hsum[tid] = 0u;
    if (tid == 0) stot = 0ULL;
    __syncthreads();

    const int gid    = blockIdx.x * blockDim.x + tid;
    const int stride = gridDim.x * blockDim.x;

    const f32x4* __restrict__ c4p = (const f32x4*)conf;
    const i32x4* __restrict__ p4p = (const i32x4*)pred;
    const i32x4* __restrict__ t4p = (const i32x4*)targ;
    const i32x4* __restrict__ m4p = (const i32x4*)mask;

    // 15 private accumulators, ALL indexing compile-time after unroll.
    int acc[NBINS];
#pragma unroll
    for (int b = 0; b < NBINS; ++b) acc[b] = 0;

    unsigned int tot = 0;

    int i = gid;
    for (; i + stride < nvec; i += 2 * stride) {
        const int j = i + stride;
        // Non-temporal: this data is touched exactly once per pass; bypassing
        // cache retention gives a clean full-HBM stream instead of the
        // hole-punched ~50% L3-hit mix (262MB FETCH at only 1.7 TB/s in R4).
        f32x4 c0 = __builtin_nontemporal_load(c4p + i);
        f32x4 c1 = __builtin_nontemporal_load(c4p + j);
        i32x4 p0 = __builtin_nontemporal_load(p4p + i);
        i32x4 p1 = __builtin_nontemporal_load(p4p + j);
        i32x4 t0 = __builtin_nontemporal_load(t4p + i);
        i32x4 t1 = __builtin_nontemporal_load(t4p + j);
        i32x4 m0 = __builtin_nontemporal_load(m4p + i);
        i32x4 m1 = __builtin_nontemporal_load(m4p + j);
        // Keep all 8 vector loads issued before consumption (MLP).
        asm volatile("" : "+v"(c0), "+v"(c1), "+v"(p0), "+v"(p1),
                          "+v"(t0), "+v"(t1), "+v"(m0), "+v"(m1));

#pragma unroll
        for (int k = 0; k < 4; ++k) {
            float c = c0[k];
            int   m = m0[k];
            tot += (unsigned int)m;
            bool valid = (m != 0) & (c > 0.0f) & (c <= 1.0f);
            int bin = (int)ceilf(c * 15.0f) - 1;
            bin = min(max(bin, 0), NBINS - 1);
            bin = valid ? bin : -1;                       // -1 matches no bin
            float corr = (p0[k] == t0[k]) ? 1.0f : 0.0f;
            int d = (int)rintf((c - corr) * 65536.0f);    // |d| <= 65536
#pragma unroll
            for (int b = 0; b < NBINS; ++b)
                acc[b] += (bin == b) ? d : 0;             // branchless select
        }
#pragma unroll
        for (int k = 0; k < 4; ++k) {
            float c = c1[k];
            int   m = m1[k];
            tot += (unsigned int)m;
            bool valid = (m != 0) & (c > 0.0f) & (c <= 1.0f);
            int bin = (int)ceilf(c * 15.0f) - 1;
            bin = min(max(bin, 0), NBINS - 1);
            bin = valid ? bin : -1;
            float corr = (p1[k] == t1[k]) ? 1.0f : 0.0f;
            int d = (int)rintf((c - corr) * 65536.0f);
#pragma unroll
            for (int b = 0; b < NBINS; ++b)
                acc[b] += (bin == b) ? d : 0;
        }
    }
    for (; i < nvec; i += stride) {
        f32x4 c0 = __builtin_nontemporal_load(c4p + i);
        i32x4 p0 = __builtin_nontemporal_load(p4p + i);
        i32x4 t0 = __builtin_nontemporal_load(t4p + i);
        i32x4 m0 = __builtin_nontemporal_load(m4p + i);
#pragma unroll
        for (int k = 0; k < 4; ++k) {
            float c = c0[k];
            int   m = m0[k];
            tot += (unsigned int)m;
            bool valid = (m != 0) & (c > 0.0f) & (c <= 1.0f);
            int bin = (int)ceilf(c * 15.0f) - 1;
            bin = min(max(bin, 0), NBINS - 1);
            bin = valid ? bin : -1;
            float corr = (p0[k] == t0[k]) ? 1.0f : 0.0f;
            int d = (int)rintf((c - corr) * 65536.0f);
#pragma unroll
            for (int b = 0; b < NBINS; ++b)
                acc[b] += (bin == b) ? d : 0;
        }
    }

    // Once-per-block merge. Wave shuffle-reduce each accumulator, then the
    // wave leader does 15 LDS atomics (4 waves x 15 RMWs -- negligible).
#pragma unroll
    for (int b = 0; b < NBINS; ++b) {
        int v = acc[b];
#pragma unroll
        for (int off = 32; off; off >>= 1) v += __shfl_down(v, off, 64);
        acc[b] = v;
    }
    unsigned int v = tot;
#pragma unroll
    for (int off = 32; off; off >>= 1) v += __shfl_down(v, off, 64);

    if (lane == 0) {
#pragma unroll
        for (int b = 0; b < NBINS; ++b)
            if (acc[b] != 0) atomicAdd(&hsum[b], (unsigned int)acc[b]);
        atomicAdd(&stot, (unsigned long long)v);
    }
    __syncthreads();

    if (tid < NBINS) {
        int s = (int)hsum[tid];   // block |sum| <= 2^30, fits i32
        if (s != 0)
            atomicAdd(&ws[tid], (unsigned long long)(long long)s);
    }
    if (tid == 0) {
        unsigned long long s = stot;
        if (s) atomicAdd(&ws[NBINS], s);
    }
}

__global__ void ece_scalar_tail(const float* __restrict__ conf,
                                const int*   __restrict__ pred,
                                const int*   __restrict__ targ,
                                const int*   __restrict__ mask,
                                unsigned long long* __restrict__ ws,
                                long long start, long long n)
{
    long long i = start + threadIdx.x;
    if (i < n) {
        float c = conf[i];
        int   m = mask[i];
        if (m) atomicAdd(&ws[NBINS], 1ULL);
        if ((m != 0) & (c > 0.0f) & (c <= 1.0f)) {
            int bin = (int)ceilf(c * 15.0f) - 1;
            bin = min(max(bin, 0), NBINS - 1);
            float corr = (pred[i] == targ[i]) ? 1.0f : 0.0f;
            int d = (int)rintf((c - corr) * 65536.0f);
            atomicAdd(&ws[bin], (unsigned long long)(long long)d);
        }
    }
}

__global__ void ece_final(const unsigned long long* __restrict__ ws,
                          float* __restrict__ out)
{
    int tid = threadIdx.x; // 64 threads
    double v = 0.0;
    if (tid < NBINS) {
        long long s = (long long)ws[tid];
        v = fabs((double)s);
    }
#pragma unroll
    for (int off = 32; off; off >>= 1) v += __shfl_down(v, off, 64);
    if (tid == 0) {
        double total = (double)ws[NBINS];
        if (total < 1.0) total = 1.0;
        out[0] = (float)(v * (1.0 / 65536.0) / total);
    }
}

extern "C" void kernel_launch(void* const* d_in, const int* in_sizes, int n_in,
                              void* d_out, int out_size, void* d_ws, size_t ws_size,
                              hipStream_t stream)
{
    const float* conf = (const float*)d_in[0];
    const int*   pred = (const int*)d_in[1];
    const int*   targ = (const int*)d_in[2];
    const int*   mask = (const int*)d_in[3];
    long long n    = in_sizes[0];
    int       nvec = (int)(n / 4);

    unsigned long long* ws = (unsigned long long*)d_ws;

    // Zero the 16 u64 accumulators every call (deterministic; capture-safe).
    hipMemsetAsync(d_ws, 0, (NBINS + 1) * sizeof(unsigned long long), stream);

    // 1536 blocks x 256 threads = 6 blocks/CU resident.
    ece_partial<<<1536, 256, 0, stream>>>(conf, pred, targ, mask, ws, nvec);
    if (n % 4 != 0) {
        ece_scalar_tail<<<1, 64, 0, stream>>>(conf, pred, targ, mask, ws,
                                              (long long)nvec * 4, n);
    }
    ece_final<<<1, 64, 0, stream>>>(ws, (float*)d_out);
}